// Round 26
// baseline (137.763 us; speedup 1.0000x reference)
//
#include <hip/hip_runtime.h>
#include <hip/hip_bf16.h>
#include <math.h>

// ---------------------------------------------------------------------------
// Expansion kernel.  Q-form fusion: out[b,uv] = sum_k Q[b,k]*LW2T[n(uv),k]
// Round 23: R18 (best spill-free k_main, 118us; total 142) + NT staging
// loads.  R22's register-deferred epilogue spilled catastrophically
// (68 persistent + ~60 working > 128 -> 470MB WRITE); reverted.
// Key re-read of evidence: R17(VGPR64) and R21(VGPR128, no spill) show the
// SAME ~85MB WRITE excess -> it is phase-A/phase-B out-line straddle RMW
// (320B rows -> 2 of 5 lines mix phases), not spill.  The eviction of
// those dirty lines is driven by the 33.5MB QF stream thrashing L2:
// __builtin_nontemporal_load on QF/AbF/A1F staging (read-once data) stops
// the pollution.  Loads only -- correctness-neutral.
// ---------------------------------------------------------------------------

typedef short bf16x8 __attribute__((ext_vector_type(8)));
typedef float f32x4 __attribute__((ext_vector_type(4)));
typedef unsigned u32x4 __attribute__((ext_vector_type(4)));

static __device__ __forceinline__ short f2bf(float f) {
  unsigned u = __builtin_bit_cast(unsigned, f);
  u = u + 0x7fffu + ((u >> 16) & 1u);   // round-to-nearest-even
  return (short)(u >> 16);
}

// ---- pre-pass 1: LW2 [64][36864] f32 -> LW2F fragment layout -------------
__global__ void k_transpose(const float* __restrict__ lw2, short* __restrict__ lw2f) {
  __shared__ float tile[64][65];
  int n0 = blockIdx.x * 64;
  int t = threadIdx.x;
#pragma unroll
  for (int k = 0; k < 16; ++k) {
    int idx = k * 256 + t;
    int c = idx >> 6, j = idx & 63;
    tile[c][j] = lw2[(size_t)c * 36864 + n0 + j];
  }
  __syncthreads();
#pragma unroll
  for (int k = 0; k < 16; ++k) {
    int idx = k * 256 + t;
    int e = idx & 7, l = (idx >> 3) & 63, half = (idx >> 9) & 1, nbl = idx >> 10;
    int q = l >> 4, colr = l & 15;
    int j = nbl * 16 + colr;
    int c = half * 32 + q * 8 + e;
    size_t nb = (size_t)(n0 >> 4) + nbl;
    lw2f[((nb * 2 + half) * 64 + l) * 8 + e] = f2bf(tile[c][j]);
  }
}

// ---- pre-pass 2: fragment-layout bias B matrices --------------------------
__global__ void k_bias(const float* __restrict__ bw2, const float* __restrict__ lb2,
                       const float* __restrict__ bb2,
                       short* __restrict__ bbf00, short* __restrict__ bbf11,
                       short* __restrict__ bbf01, short* __restrict__ bbf10) {
  int i = blockIdx.x * 256 + threadIdx.x;
  if (i < 98304) {                       // BBF00
    int uvb = i / 1536, r = i % 1536;
    int kk = r >> 9, l = (r >> 3) & 63, e = r & 7;
    int q = l >> 4, col = l & 15;
    int uv = uvb * 16 + col, k = kk * 32 + q * 8 + e;
    float v = 0.0f;
    if (k < 64) v = bw2[k * 1280 + uv];
    else if (k < 80) v = lb2[(k - 64) * 1024 + uv];
    else if (k == 80) v = bb2[uv];
    bbf00[i] = f2bf(v);
  } else if (i < 122880) {               // BBF11
    int j = i - 98304;
    int uvb = j / 1536, r = j % 1536;
    int kk = r >> 9, l = (r >> 3) & 63, e = r & 7;
    int q = l >> 4, col = l & 15;
    int uv = uvb * 16 + col, k = kk * 32 + q * 8 + e;
    float v = 0.0f;
    if (k < 64) v = bw2[k * 1280 + 1024 + uv];
    else if (k < 80) v = lb2[16384 + (k - 64) * 256 + uv];
    else if (k == 80) v = bb2[1024 + uv];
    bbf11[j] = f2bf(v);
  } else if (i < 139264) {               // BBF01
    int j = i - 122880;
    int uvb = j >> 9, r = j & 511;
    int l = (r >> 3) & 63, e = r & 7;
    int q = l >> 4, col = l & 15;
    int uv = uvb * 16 + col, k = q * 8 + e;
    bbf01[j] = (k < 16) ? f2bf(lb2[20480 + k * 512 + uv]) : (short)0;
  } else if (i < 155648) {               // BBF10
    int j = i - 139264;
    int uvb = j >> 9, r = j & 511;
    int l = (r >> 3) & 63, e = r & 7;
    int q = l >> 4, col = l & 15;
    int uv = uvb * 16 + col, k = q * 8 + e;
    bbf10[j] = (k < 16) ? f2bf(lb2[28672 + k * 512 + uv]) : (short)0;
  }
}

// ---- pre-pass 3: per-sample h, h2, x0, x1 --------------------------------
__global__ void k_samples(const float* __restrict__ feat, const float* __restrict__ ne,
                          const float* __restrict__ W0, const float* __restrict__ W1,
                          const float* __restrict__ lw1, const float* __restrict__ lb1,
                          const float* __restrict__ bw1, const float* __restrict__ bb1,
                          float* __restrict__ H, float* __restrict__ H2,
                          float* __restrict__ X0, float* __restrict__ X1) {
  int b = blockIdx.x;
  int t = threadIdx.x;               // 192 threads
  __shared__ float sne[128];
  __shared__ float sf[320];
  if (t < 128) sne[t] = ne[(size_t)b * 128 + t];
  for (int i = t; i < 320; i += 192) sf[i] = feat[(size_t)b * 320 + i];
  __syncthreads();
  if (t < 64) {
    float a = lb1[t];
    for (int k = 0; k < 128; ++k) a += sne[k] * lw1[k * 64 + t];
    H[(size_t)b * 64 + t] = a / (1.0f + expf(-a));
  } else if (t < 128) {
    int c = t - 64;
    float a = bb1[c];
    for (int k = 0; k < 128; ++k) a += sne[k] * bw1[k * 64 + c];
    H2[(size_t)b * 64 + c] = a / (1.0f + expf(-a));
  } else if (t < 144) {
    int v = t - 128;
    float a = 0.0f;
    for (int u = 0; u < 128; ++u) a += sf[u] * W0[u * 16 + v];
    X0[(size_t)b * 16 + v] = a * 0.08838834764831845f;  // 1/sqrt(128)
  } else {
    int idx = t - 144, v = idx / 3, j = idx % 3;        // idx < 48
    float a = 0.0f;
    for (int u = 0; u < 64; ++u) a += sf[128 + u * 3 + j] * W1[u * 16 + v];
    X1[(size_t)b * 48 + v * 3 + j] = a * 0.125f;        // 1/sqrt(64)
  }
}

// ---- pre-pass 4: Q-plane + A-side bias fragments (bf16, global) ----------
__global__ void k_q(const float* __restrict__ H, const float* __restrict__ H2,
                    const float* __restrict__ X0, const float* __restrict__ X1,
                    short* __restrict__ QF, short* __restrict__ AbF,
                    short* __restrict__ A1F) {
  int bid = blockIdx.x;
  int g16 = bid >> 3, part = bid & 7;
  int b0 = g16 * 16;
  int t = threadIdx.x;               // 256 threads
  __shared__ float sH[16][64];
  __shared__ float sH2[16][64];
  __shared__ float sX0[16][16];
  __shared__ float sX1[16][48];
  for (int i = t; i < 1024; i += 256) {
    sH [i >> 6][i & 63] = H [(size_t)(b0 + (i >> 6)) * 64 + (i & 63)];
    sH2[i >> 6][i & 63] = H2[(size_t)(b0 + (i >> 6)) * 64 + (i & 63)];
  }
  sX0[t >> 4][t & 15] = X0[(size_t)(b0 + (t >> 4)) * 16 + (t & 15)];
  for (int i = t; i < 768; i += 256)
    sX1[i / 48][i % 48] = X1[(size_t)(b0 + i / 48) * 48 + (i % 48)];
  __syncthreads();
#pragma unroll
  for (int it = 0; it < 16; ++it) {
    int i = part * 4096 + it * 256 + t;
    int p = i >> 13, rem = i & 8191;
    int kk = rem >> 8, lane = (rem >> 2) & 63, e2 = (rem & 3) << 1;
    int cc = lane & 15, q = lane >> 4;
    int k = kk * 32 + q * 8 + e2;
    int w = k >> 6, c = k & 63;
    float xw = (p == 0) ? sX0[cc][w] : sX1[cc][w * 3 + (p - 1)];
    unsigned lo = (unsigned short)f2bf(sH[cc][c] * xw);
    unsigned hi = (unsigned short)f2bf(sH[cc][c + 1] * xw);
    ((unsigned*)QF)[(size_t)g16 * 32768 + i] = lo | (hi << 16);
  }
  if (part == 0) {
    for (int i = t; i < 1536; i += 256) {  // AbF
      int kk = i >> 9, lane = (i >> 3) & 63, e = i & 7;
      int cc = lane & 15, q = lane >> 4;
      int k = kk * 32 + q * 8 + e;
      float v = 0.0f;
      if (k < 64) v = sH2[cc][k];
      else if (k < 80) v = sX0[cc][k - 64];
      else if (k == 80) v = 1.0f;
      AbF[(size_t)g16 * 1536 + i] = f2bf(v);
    }
  } else if (part == 1) {
    for (int i = t; i < 1536; i += 256) {  // A1F [j<3][lane][8]
      int j = i >> 9, r = i & 511;
      int lane = r >> 3, e = r & 7;
      int cc = lane & 15, q = lane >> 4;
      int k = q * 8 + e;
      A1F[(size_t)g16 * 1536 + i] = (k < 16) ? f2bf(sX1[cc][k * 3 + j]) : (short)0;
    }
  }
}

// ---- MFMA helpers ----------------------------------------------------------
template <int NP, int N, int NB16, int NS16>
static __device__ __forceinline__ void mm_stream(
    const short* __restrict__ LW2F, const short* __restrict__ sQ0,
    int uvb, int lane8, f32x4 (&acc)[NP][N]) {
  auto bptr = [&](int kk, int i) -> const bf16x8* {
    return (const bf16x8*)(LW2F +
        ((size_t)(NB16 + (kk >> 1) * NS16 + uvb + i) * 2 + (kk & 1)) * 512 + lane8);
  };
  bf16x8 B[2][N];
#pragma unroll
  for (int d = 0; d < 2; ++d)
#pragma unroll
    for (int i = 0; i < N; ++i) B[d][i] = *bptr(d, i);
#pragma unroll
  for (int kk = 0; kk < 32; ++kk) {
    const int d = kk & 1;
    bf16x8 A[NP];
#pragma unroll
    for (int p = 0; p < NP; ++p)
      A[p] = *(const bf16x8*)(sQ0 + p * 16384 + kk * 512 + lane8);
#pragma unroll
    for (int i = 0; i < N; ++i)
#pragma unroll
      for (int p = 0; p < NP; ++p)
        acc[p][i] = __builtin_amdgcn_mfma_f32_16x16x32_bf16(A[p], B[d][i], acc[p][i], 0, 0, 0);
    if (kk + 2 < 32) {
#pragma unroll
      for (int i = 0; i < N; ++i) B[d][i] = *bptr(kk + 2, i);
    }
  }
}

template <int NP, int N, int NBIAS>
static __device__ __forceinline__ void mm_bias(
    const short* __restrict__ BBF, const short* __restrict__ Ab0, int astride,
    int uvb, int lane8, f32x4 (&acc)[NP][N]) {
#pragma unroll
  for (int kk = 0; kk < NBIAS; ++kk)
#pragma unroll
    for (int i = 0; i < N; ++i) {
      const bf16x8 Bx = *(const bf16x8*)(BBF + (size_t)((uvb + i) * NBIAS + kk) * 512 + lane8);
#pragma unroll
      for (int p = 0; p < NP; ++p) {
        const bf16x8 Ap = *(const bf16x8*)(Ab0 + p * astride + kk * 512 + lane8);
        acc[p][i] = __builtin_amdgcn_mfma_f32_16x16x32_bf16(Ap, Bx, acc[p][i], 0, 0, 0);
      }
    }
}

__global__ __launch_bounds__(1024, 1) void k_main(
    const short* __restrict__ LW2F,
    const short* __restrict__ BBF00, const short* __restrict__ BBF11,
    const short* __restrict__ BBF01, const short* __restrict__ BBF10,
    const short* __restrict__ QF, const short* __restrict__ AbF,
    const short* __restrict__ A1F, float* __restrict__ out) {
  constexpr float S00 = 0.0625f;                  // 1/16
  constexpr float S3 = 0.036084391824351614f;     // (1/sqrt(3))/16

  // blockIdx = xslot + 8*seq, xslot = (s&3) + 4*h  ->  XCD = xslot:
  // XCDs 0..3 only read B-half 0, XCDs 4..7 only half 1 (L2-resident).
  int bidx = blockIdx.x;
  int xslot = bidx & 7;
  int h = xslot >> 2;
  int s = (xslot & 3) + 4 * (bidx >> 3);   // 0..127
  int b0 = s << 5;                          // 32 samples per tile
  int t = threadIdx.x;                      // 1024 threads = 16 slots
  int lane = t & 63, slot = t >> 6;
  int col = lane & 15, q = lane >> 4;
  int lane8 = lane * 8;

  __shared__ short sQ[4 * 16384];   // 128 KB: 4 passive Q planes
  __shared__ short sAb[2 * 1536];   // 6 KB: phase-A bias planes (g0,g1)
  __shared__ short sA1[6 * 512];    // 6 KB: phase-B bias planes (j,g)

  // ---- stage bias planes (once) + phase-A Q planes (Q0 g0, Q0 g1) --------
  // All staging loads are NON-TEMPORAL: read-once data must not evict
  // dirty out lines or the L2-resident B panels.
  for (int i = t; i < 384; i += 1024) {
    int g = i >= 192, r = i - g * 192;
    ((u32x4*)(sAb + g * 1536))[r] =
        __builtin_nontemporal_load(((const u32x4*)(AbF + (size_t)(s * 2 + g) * 1536)) + r);
  }
  for (int i = t; i < 384; i += 1024) {
    int jp = i >> 6, r = i & 63;          // jp = j*2+g
    int j = jp >> 1, g = jp & 1;
    ((u32x4*)(sA1 + jp * 512))[r] =
        __builtin_nontemporal_load(((const u32x4*)(A1F + ((size_t)(s * 2 + g) * 3 + j) * 512)) + r);
  }
  for (int i = t; i < 4096; i += 1024) {
    int pl = i >> 11, r = i & 2047;       // pl = g
    const u32x4* src = (const u32x4*)(QF + (size_t)(s * 2 + pl) * 65536);
    ((u32x4*)sQ)[pl * 2048 + r] = __builtin_nontemporal_load(src + r);
  }
  __syncthreads();

  // ===== phase A: path00 (uv-half 512, slot owns 32) ======================
  {
    int uvb = h * 32 + slot * 2;
    f32x4 acc[2][2] = {};
    mm_stream<2, 2, 0, 64>(LW2F, sQ, uvb, lane8, acc);
    mm_bias<2, 2, 3>(BBF00, sAb, 1536, uvb, lane8, acc);
#pragma unroll
    for (int g = 0; g < 2; ++g)
#pragma unroll
      for (int i = 0; i < 2; ++i)
#pragma unroll
        for (int ii = 0; ii < 4; ++ii) {
          size_t ob = (size_t)(b0 + g * 16 + q * 4 + ii) * 6400;
          int uv = (uvb + i) * 16 + col;
          out[ob + (uv >> 5) * 80 + (uv & 31)] = acc[g][i][ii] * S00;
        }
  }
  // path11 (uv-half 128, slots 0..7)
  if (slot < 8) {
    int uvb = h * 8 + slot;
    f32x4 acc[2][1] = {};
    mm_stream<2, 1, 1024, 16>(LW2F, sQ, uvb, lane8, acc);
    mm_bias<2, 1, 3>(BBF11, sAb, 1536, uvb, lane8, acc);
#pragma unroll
    for (int g = 0; g < 2; ++g)
#pragma unroll
      for (int ii = 0; ii < 4; ++ii) {
        size_t ob = (size_t)(b0 + g * 16 + q * 4 + ii) * 6400;
        int uv = uvb * 16 + col;
        float val = acc[g][0][ii] * S3;
        int u = uv >> 4, v = uv & 15;
        float* p = out + ob + (size_t)(32 + 3 * u) * 80 + (32 + 3 * v);
        p[0] = val;   p[1] = 0.f;   p[2] = 0.f;
        p[80] = 0.f;  p[81] = val;  p[82] = 0.f;
        p[160] = 0.f; p[161] = 0.f; p[162] = val;
      }
  }

  // ===== phase B pass 1: planes (j,g) = (0,0),(0,1),(1,0),(1,1) ===========
  __syncthreads();
  for (int i = t; i < 8192; i += 1024) {
    int pl = i >> 11, r = i & 2047;       // pl = j*2+g
    const u32x4* src = (const u32x4*)(QF +
        ((size_t)(s * 2 + (pl & 1)) * 4 + 1 + (pl >> 1)) * 16384);
    ((u32x4*)sQ)[pl * 2048 + r] = __builtin_nontemporal_load(src + r);
  }
  __syncthreads();
  {
    int uvb = h * 16 + slot;
    {
      f32x4 acc[4][1] = {};
      mm_stream<4, 1, 1280, 32>(LW2F, sQ, uvb, lane8, acc);
      mm_bias<4, 1, 1>(BBF01, sA1, 512, uvb, lane8, acc);
#pragma unroll
      for (int p = 0; p < 4; ++p)
#pragma unroll
        for (int ii = 0; ii < 4; ++ii) {
          int j = p >> 1, g = p & 1;
          size_t ob = (size_t)(b0 + g * 16 + q * 4 + ii) * 6400;
          int uv = uvb * 16 + col;
          out[ob + (uv >> 4) * 80 + 32 + 3 * (uv & 15) + j] = acc[p][0][ii] * S3;
        }
    }
    {
      f32x4 acc[4][1] = {};
      mm_stream<4, 1, 1792, 32>(LW2F, sQ, uvb, lane8, acc);
      mm_bias<4, 1, 1>(BBF10, sA1, 512, uvb, lane8, acc);
#pragma unroll
      for (int p = 0; p < 4; ++p)
#pragma unroll
        for (int ii = 0; ii < 4; ++ii) {
          int j = p >> 1, g = p & 1;
          size_t ob = (size_t)(b0 + g * 16 + q * 4 + ii) * 6400;
          int uv = uvb * 16 + col;
          out[ob + (size_t)(32 + 3 * (uv >> 5) + j) * 80 + (uv & 31)] = acc[p][0][ii] * S3;
        }
    }
  }

  // ===== phase B pass 2: planes (j=2, g=0,1) ==============================
  __syncthreads();
  for (int i = t; i < 4096; i += 1024) {
    int pl = i >> 11, r = i & 2047;       // pl = g
    const u32x4* src = (const u32x4*)(QF + ((size_t)(s * 2 + pl) * 4 + 3) * 16384);
    ((u32x4*)sQ)[pl * 2048 + r] = __builtin_nontemporal_load(src + r);
  }
  __syncthreads();
  {
    int uvb = h * 16 + slot;
    {
      f32x4 acc[2][1] = {};
      mm_stream<2, 1, 1280, 32>(LW2F, sQ, uvb, lane8, acc);
      mm_bias<2, 1, 1>(BBF01, sA1 + 4 * 512, 512, uvb, lane8, acc);
#pragma unroll
      for (int g = 0; g < 2; ++g)
#pragma unroll
        for (int ii = 0; ii < 4; ++ii) {
          size_t ob = (size_t)(b0 + g * 16 + q * 4 + ii) * 6400;
          int uv = uvb * 16 + col;
          out[ob + (uv >> 4) * 80 + 32 + 3 * (uv & 15) + 2] = acc[g][0][ii] * S3;
        }
    }
    {
      f32x4 acc[2][1] = {};
      mm_stream<2, 1, 1792, 32>(LW2F, sQ, uvb, lane8, acc);
      mm_bias<2, 1, 1>(BBF10, sA1 + 4 * 512, 512, uvb, lane8, acc);
#pragma unroll
      for (int g = 0; g < 2; ++g)
#pragma unroll
        for (int ii = 0; ii < 4; ++ii) {
          size_t ob = (size_t)(b0 + g * 16 + q * 4 + ii) * 6400;
          int uv = uvb * 16 + col;
          out[ob + (size_t)(32 + 3 * (uv >> 5) + 2) * 80 + (uv & 31)] = acc[g][0][ii] * S3;
        }
    }
  }
}

// ---------------------------------------------------------------------------
extern "C" void kernel_launch(void* const* d_in, const int* in_sizes, int n_in,
                              void* d_out, int out_size, void* d_ws, size_t ws_size,
                              hipStream_t stream) {
  const float* feat = (const float*)d_in[0];
  const float* ne   = (const float*)d_in[1];
  const float* W0   = (const float*)d_in[2];
  const float* W1   = (const float*)d_in[3];
  const float* lw1  = (const float*)d_in[4];
  const float* lb1  = (const float*)d_in[5];
  const float* lw2  = (const float*)d_in[6];
  const float* lb2  = (const float*)d_in[7];
  const float* bw1  = (const float*)d_in[8];
  const float* bb1  = (const float*)d_in[9];
  const float* bw2  = (const float*)d_in[10];
  const float* bb2  = (const float*)d_in[11];

  char* ws = (char*)d_ws;
  short* LW2F  = (short*)ws; ws += (size_t)36864 * 64 * 2;   // 4.72 MB
  short* BBF00 = (short*)ws; ws += (size_t)98304 * 2;
  short* BBF11 = (short*)ws; ws += (size_t)24576 * 2;
  short* BBF01 = (short*)ws; ws += (size_t)16384 * 2;
  short* BBF10 = (short*)ws; ws += (size_t)16384 * 2;
  float* H  = (float*)ws;   ws += (size_t)4096 * 64 * 4;
  float* H2 = (float*)ws;   ws += (size_t)4096 * 64 * 4;
  float* X0 = (float*)ws;   ws += (size_t)4096 * 16 * 4;
  float* X1 = (float*)ws;   ws += (size_t)4096 * 48 * 4;
  short* QF  = (short*)ws;  ws += (size_t)256 * 65536 * 2;   // 33.55 MB
  short* AbF = (short*)ws;  ws += (size_t)256 * 1536 * 2;
  short* A1F = (short*)ws;  ws += (size_t)256 * 1536 * 2;
  (void)ws_size; (void)in_sizes; (void)n_in; (void)out_size;

  hipLaunchKernelGGL(k_transpose, dim3(576), dim3(256), 0, stream, lw2, LW2F);
  hipLaunchKernelGGL(k_bias, dim3(608), dim3(256), 0, stream, bw2, lb2, bb2,
                     BBF00, BBF11, BBF01, BBF10);
  hipLaunchKernelGGL(k_samples, dim3(4096), dim3(192), 0, stream,
                     feat, ne, W0, W1, lw1, lb1, bw1, bb1, H, H2, X0, X1);
  hipLaunchKernelGGL(k_q, dim3(2048), dim3(256), 0, stream,
                     H, H2, X0, X1, QF, AbF, A1F);
  hipLaunchKernelGGL(k_main, dim3(256), dim3(1024), 0, stream,
                     LW2F, BBF00, BBF11, BBF01, BBF10, QF, AbF, A1F, (float*)d_out);
}

// Round 27
// 136.147 us; speedup vs baseline: 1.0119x; 1.0119x over previous
//
#include <hip/hip_runtime.h>
#include <hip/hip_bf16.h>
#include <math.h>

// ---------------------------------------------------------------------------
// Expansion kernel.  Q-form fusion: out[b,uv] = sum_k Q[b,k]*LW2T[n(uv),k]
// Round 23: R18 (best spill-free k_main, 118us; total 142) + NT staging
// loads.  R22's register-deferred epilogue spilled catastrophically
// (68 persistent + ~60 working > 128 -> 470MB WRITE); reverted.
// Key re-read of evidence: R17(VGPR64) and R21(VGPR128, no spill) show the
// SAME ~85MB WRITE excess -> it is phase-A/phase-B out-line straddle RMW
// (320B rows -> 2 of 5 lines mix phases), not spill.  The eviction of
// those dirty lines is driven by the 33.5MB QF stream thrashing L2:
// __builtin_nontemporal_load on QF/AbF/A1F staging (read-once data) stops
// the pollution.  Loads only -- correctness-neutral.
// ---------------------------------------------------------------------------

typedef short bf16x8 __attribute__((ext_vector_type(8)));
typedef float f32x4 __attribute__((ext_vector_type(4)));
typedef unsigned u32x4 __attribute__((ext_vector_type(4)));

static __device__ __forceinline__ short f2bf(float f) {
  unsigned u = __builtin_bit_cast(unsigned, f);
  u = u + 0x7fffu + ((u >> 16) & 1u);   // round-to-nearest-even
  return (short)(u >> 16);
}

// ---- pre-pass 1: LW2 [64][36864] f32 -> LW2F fragment layout -------------
__global__ void k_transpose(const float* __restrict__ lw2, short* __restrict__ lw2f) {
  __shared__ float tile[64][65];
  int n0 = blockIdx.x * 64;
  int t = threadIdx.x;
#pragma unroll
  for (int k = 0; k < 16; ++k) {
    int idx = k * 256 + t;
    int c = idx >> 6, j = idx & 63;
    tile[c][j] = lw2[(size_t)c * 36864 + n0 + j];
  }
  __syncthreads();
#pragma unroll
  for (int k = 0; k < 16; ++k) {
    int idx = k * 256 + t;
    int e = idx & 7, l = (idx >> 3) & 63, half = (idx >> 9) & 1, nbl = idx >> 10;
    int q = l >> 4, colr = l & 15;
    int j = nbl * 16 + colr;
    int c = half * 32 + q * 8 + e;
    size_t nb = (size_t)(n0 >> 4) + nbl;
    lw2f[((nb * 2 + half) * 64 + l) * 8 + e] = f2bf(tile[c][j]);
  }
}

// ---- pre-pass 2: fragment-layout bias B matrices --------------------------
__global__ void k_bias(const float* __restrict__ bw2, const float* __restrict__ lb2,
                       const float* __restrict__ bb2,
                       short* __restrict__ bbf00, short* __restrict__ bbf11,
                       short* __restrict__ bbf01, short* __restrict__ bbf10) {
  int i = blockIdx.x * 256 + threadIdx.x;
  if (i < 98304) {                       // BBF00
    int uvb = i / 1536, r = i % 1536;
    int kk = r >> 9, l = (r >> 3) & 63, e = r & 7;
    int q = l >> 4, col = l & 15;
    int uv = uvb * 16 + col, k = kk * 32 + q * 8 + e;
    float v = 0.0f;
    if (k < 64) v = bw2[k * 1280 + uv];
    else if (k < 80) v = lb2[(k - 64) * 1024 + uv];
    else if (k == 80) v = bb2[uv];
    bbf00[i] = f2bf(v);
  } else if (i < 122880) {               // BBF11
    int j = i - 98304;
    int uvb = j / 1536, r = j % 1536;
    int kk = r >> 9, l = (r >> 3) & 63, e = r & 7;
    int q = l >> 4, col = l & 15;
    int uv = uvb * 16 + col, k = kk * 32 + q * 8 + e;
    float v = 0.0f;
    if (k < 64) v = bw2[k * 1280 + 1024 + uv];
    else if (k < 80) v = lb2[16384 + (k - 64) * 256 + uv];
    else if (k == 80) v = bb2[1024 + uv];
    bbf11[j] = f2bf(v);
  } else if (i < 139264) {               // BBF01
    int j = i - 122880;
    int uvb = j >> 9, r = j & 511;
    int l = (r >> 3) & 63, e = r & 7;
    int q = l >> 4, col = l & 15;
    int uv = uvb * 16 + col, k = q * 8 + e;
    bbf01[j] = (k < 16) ? f2bf(lb2[20480 + k * 512 + uv]) : (short)0;
  } else if (i < 155648) {               // BBF10
    int j = i - 139264;
    int uvb = j >> 9, r = j & 511;
    int l = (r >> 3) & 63, e = r & 7;
    int q = l >> 4, col = l & 15;
    int uv = uvb * 16 + col, k = q * 8 + e;
    bbf10[j] = (k < 16) ? f2bf(lb2[28672 + k * 512 + uv]) : (short)0;
  }
}

// ---- pre-pass 3: per-sample h, h2, x0, x1 --------------------------------
__global__ void k_samples(const float* __restrict__ feat, const float* __restrict__ ne,
                          const float* __restrict__ W0, const float* __restrict__ W1,
                          const float* __restrict__ lw1, const float* __restrict__ lb1,
                          const float* __restrict__ bw1, const float* __restrict__ bb1,
                          float* __restrict__ H, float* __restrict__ H2,
                          float* __restrict__ X0, float* __restrict__ X1) {
  int b = blockIdx.x;
  int t = threadIdx.x;               // 192 threads
  __shared__ float sne[128];
  __shared__ float sf[320];
  if (t < 128) sne[t] = ne[(size_t)b * 128 + t];
  for (int i = t; i < 320; i += 192) sf[i] = feat[(size_t)b * 320 + i];
  __syncthreads();
  if (t < 64) {
    float a = lb1[t];
    for (int k = 0; k < 128; ++k) a += sne[k] * lw1[k * 64 + t];
    H[(size_t)b * 64 + t] = a / (1.0f + expf(-a));
  } else if (t < 128) {
    int c = t - 64;
    float a = bb1[c];
    for (int k = 0; k < 128; ++k) a += sne[k] * bw1[k * 64 + c];
    H2[(size_t)b * 64 + c] = a / (1.0f + expf(-a));
  } else if (t < 144) {
    int v = t - 128;
    float a = 0.0f;
    for (int u = 0; u < 128; ++u) a += sf[u] * W0[u * 16 + v];
    X0[(size_t)b * 16 + v] = a * 0.08838834764831845f;  // 1/sqrt(128)
  } else {
    int idx = t - 144, v = idx / 3, j = idx % 3;        // idx < 48
    float a = 0.0f;
    for (int u = 0; u < 64; ++u) a += sf[128 + u * 3 + j] * W1[u * 16 + v];
    X1[(size_t)b * 48 + v * 3 + j] = a * 0.125f;        // 1/sqrt(64)
  }
}

// ---- pre-pass 4: Q-plane + A-side bias fragments (bf16, global) ----------
__global__ void k_q(const float* __restrict__ H, const float* __restrict__ H2,
                    const float* __restrict__ X0, const float* __restrict__ X1,
                    short* __restrict__ QF, short* __restrict__ AbF,
                    short* __restrict__ A1F) {
  int bid = blockIdx.x;
  int g16 = bid >> 3, part = bid & 7;
  int b0 = g16 * 16;
  int t = threadIdx.x;               // 256 threads
  __shared__ float sH[16][64];
  __shared__ float sH2[16][64];
  __shared__ float sX0[16][16];
  __shared__ float sX1[16][48];
  for (int i = t; i < 1024; i += 256) {
    sH [i >> 6][i & 63] = H [(size_t)(b0 + (i >> 6)) * 64 + (i & 63)];
    sH2[i >> 6][i & 63] = H2[(size_t)(b0 + (i >> 6)) * 64 + (i & 63)];
  }
  sX0[t >> 4][t & 15] = X0[(size_t)(b0 + (t >> 4)) * 16 + (t & 15)];
  for (int i = t; i < 768; i += 256)
    sX1[i / 48][i % 48] = X1[(size_t)(b0 + i / 48) * 48 + (i % 48)];
  __syncthreads();
#pragma unroll
  for (int it = 0; it < 16; ++it) {
    int i = part * 4096 + it * 256 + t;
    int p = i >> 13, rem = i & 8191;
    int kk = rem >> 8, lane = (rem >> 2) & 63, e2 = (rem & 3) << 1;
    int cc = lane & 15, q = lane >> 4;
    int k = kk * 32 + q * 8 + e2;
    int w = k >> 6, c = k & 63;
    float xw = (p == 0) ? sX0[cc][w] : sX1[cc][w * 3 + (p - 1)];
    unsigned lo = (unsigned short)f2bf(sH[cc][c] * xw);
    unsigned hi = (unsigned short)f2bf(sH[cc][c + 1] * xw);
    ((unsigned*)QF)[(size_t)g16 * 32768 + i] = lo | (hi << 16);
  }
  if (part == 0) {
    for (int i = t; i < 1536; i += 256) {  // AbF
      int kk = i >> 9, lane = (i >> 3) & 63, e = i & 7;
      int cc = lane & 15, q = lane >> 4;
      int k = kk * 32 + q * 8 + e;
      float v = 0.0f;
      if (k < 64) v = sH2[cc][k];
      else if (k < 80) v = sX0[cc][k - 64];
      else if (k == 80) v = 1.0f;
      AbF[(size_t)g16 * 1536 + i] = f2bf(v);
    }
  } else if (part == 1) {
    for (int i = t; i < 1536; i += 256) {  // A1F [j<3][lane][8]
      int j = i >> 9, r = i & 511;
      int lane = r >> 3, e = r & 7;
      int cc = lane & 15, q = lane >> 4;
      int k = q * 8 + e;
      A1F[(size_t)g16 * 1536 + i] = (k < 16) ? f2bf(sX1[cc][k * 3 + j]) : (short)0;
    }
  }
}

// ---- MFMA helpers ----------------------------------------------------------
template <int NP, int N, int NB16, int NS16>
static __device__ __forceinline__ void mm_stream(
    const short* __restrict__ LW2F, const short* __restrict__ sQ0,
    int uvb, int lane8, f32x4 (&acc)[NP][N]) {
  auto bptr = [&](int kk, int i) -> const bf16x8* {
    return (const bf16x8*)(LW2F +
        ((size_t)(NB16 + (kk >> 1) * NS16 + uvb + i) * 2 + (kk & 1)) * 512 + lane8);
  };
  bf16x8 B[2][N];
#pragma unroll
  for (int d = 0; d < 2; ++d)
#pragma unroll
    for (int i = 0; i < N; ++i) B[d][i] = *bptr(d, i);
#pragma unroll
  for (int kk = 0; kk < 32; ++kk) {
    const int d = kk & 1;
    bf16x8 A[NP];
#pragma unroll
    for (int p = 0; p < NP; ++p)
      A[p] = *(const bf16x8*)(sQ0 + p * 16384 + kk * 512 + lane8);
#pragma unroll
    for (int i = 0; i < N; ++i)
#pragma unroll
      for (int p = 0; p < NP; ++p)
        acc[p][i] = __builtin_amdgcn_mfma_f32_16x16x32_bf16(A[p], B[d][i], acc[p][i], 0, 0, 0);
    if (kk + 2 < 32) {
#pragma unroll
      for (int i = 0; i < N; ++i) B[d][i] = *bptr(kk + 2, i);
    }
  }
}

template <int NP, int N, int NBIAS>
static __device__ __forceinline__ void mm_bias(
    const short* __restrict__ BBF, const short* __restrict__ Ab0, int astride,
    int uvb, int lane8, f32x4 (&acc)[NP][N]) {
#pragma unroll
  for (int kk = 0; kk < NBIAS; ++kk)
#pragma unroll
    for (int i = 0; i < N; ++i) {
      const bf16x8 Bx = *(const bf16x8*)(BBF + (size_t)((uvb + i) * NBIAS + kk) * 512 + lane8);
#pragma unroll
      for (int p = 0; p < NP; ++p) {
        const bf16x8 Ap = *(const bf16x8*)(Ab0 + p * astride + kk * 512 + lane8);
        acc[p][i] = __builtin_amdgcn_mfma_f32_16x16x32_bf16(Ap, Bx, acc[p][i], 0, 0, 0);
      }
    }
}

__global__ __launch_bounds__(1024, 1) void k_main(
    const short* __restrict__ LW2F,
    const short* __restrict__ BBF00, const short* __restrict__ BBF11,
    const short* __restrict__ BBF01, const short* __restrict__ BBF10,
    const short* __restrict__ QF, const short* __restrict__ AbF,
    const short* __restrict__ A1F, float* __restrict__ out) {
  constexpr float S00 = 0.0625f;                  // 1/16
  constexpr float S3 = 0.036084391824351614f;     // (1/sqrt(3))/16

  // blockIdx = xslot + 8*seq, xslot = (s&3) + 4*h  ->  XCD = xslot:
  // XCDs 0..3 only read B-half 0, XCDs 4..7 only half 1 (L2-resident).
  int bidx = blockIdx.x;
  int xslot = bidx & 7;
  int h = xslot >> 2;
  int s = (xslot & 3) + 4 * (bidx >> 3);   // 0..127
  int b0 = s << 5;                          // 32 samples per tile
  int t = threadIdx.x;                      // 1024 threads = 16 slots
  int lane = t & 63, slot = t >> 6;
  int col = lane & 15, q = lane >> 4;
  int lane8 = lane * 8;

  __shared__ short sQ[4 * 16384];   // 128 KB: 4 passive Q planes
  __shared__ short sAb[2 * 1536];   // 6 KB: phase-A bias planes (g0,g1)
  __shared__ short sA1[6 * 512];    // 6 KB: phase-B bias planes (j,g)

  // ---- stage bias planes (once) + phase-A Q planes (Q0 g0, Q0 g1) --------
  // All staging loads are NON-TEMPORAL: read-once data must not evict
  // dirty out lines or the L2-resident B panels.
  for (int i = t; i < 384; i += 1024) {
    int g = i >= 192, r = i - g * 192;
    ((u32x4*)(sAb + g * 1536))[r] =
        __builtin_nontemporal_load(((const u32x4*)(AbF + (size_t)(s * 2 + g) * 1536)) + r);
  }
  for (int i = t; i < 384; i += 1024) {
    int jp = i >> 6, r = i & 63;          // jp = j*2+g
    int j = jp >> 1, g = jp & 1;
    ((u32x4*)(sA1 + jp * 512))[r] =
        __builtin_nontemporal_load(((const u32x4*)(A1F + ((size_t)(s * 2 + g) * 3 + j) * 512)) + r);
  }
  for (int i = t; i < 4096; i += 1024) {
    int pl = i >> 11, r = i & 2047;       // pl = g
    const u32x4* src = (const u32x4*)(QF + (size_t)(s * 2 + pl) * 65536);
    ((u32x4*)sQ)[pl * 2048 + r] = __builtin_nontemporal_load(src + r);
  }
  __syncthreads();

  // ===== phase A: path00 (uv-half 512, slot owns 32) ======================
  {
    int uvb = h * 32 + slot * 2;
    f32x4 acc[2][2] = {};
    mm_stream<2, 2, 0, 64>(LW2F, sQ, uvb, lane8, acc);
    mm_bias<2, 2, 3>(BBF00, sAb, 1536, uvb, lane8, acc);
#pragma unroll
    for (int g = 0; g < 2; ++g)
#pragma unroll
      for (int i = 0; i < 2; ++i)
#pragma unroll
        for (int ii = 0; ii < 4; ++ii) {
          size_t ob = (size_t)(b0 + g * 16 + q * 4 + ii) * 6400;
          int uv = (uvb + i) * 16 + col;
          out[ob + (uv >> 5) * 80 + (uv & 31)] = acc[g][i][ii] * S00;
        }
  }
  // path11 (uv-half 128, slots 0..7)
  if (slot < 8) {
    int uvb = h * 8 + slot;
    f32x4 acc[2][1] = {};
    mm_stream<2, 1, 1024, 16>(LW2F, sQ, uvb, lane8, acc);
    mm_bias<2, 1, 3>(BBF11, sAb, 1536, uvb, lane8, acc);
#pragma unroll
    for (int g = 0; g < 2; ++g)
#pragma unroll
      for (int ii = 0; ii < 4; ++ii) {
        size_t ob = (size_t)(b0 + g * 16 + q * 4 + ii) * 6400;
        int uv = uvb * 16 + col;
        float val = acc[g][0][ii] * S3;
        int u = uv >> 4, v = uv & 15;
        float* p = out + ob + (size_t)(32 + 3 * u) * 80 + (32 + 3 * v);
        p[0] = val;   p[1] = 0.f;   p[2] = 0.f;
        p[80] = 0.f;  p[81] = val;  p[82] = 0.f;
        p[160] = 0.f; p[161] = 0.f; p[162] = val;
      }
  }

  // ===== phase B pass 1: planes (j,g) = (0,0),(0,1),(1,0),(1,1) ===========
  __syncthreads();
  for (int i = t; i < 8192; i += 1024) {
    int pl = i >> 11, r = i & 2047;       // pl = j*2+g
    const u32x4* src = (const u32x4*)(QF +
        ((size_t)(s * 2 + (pl & 1)) * 4 + 1 + (pl >> 1)) * 16384);
    ((u32x4*)sQ)[pl * 2048 + r] = __builtin_nontemporal_load(src + r);
  }
  __syncthreads();
  {
    int uvb = h * 16 + slot;
    {
      f32x4 acc[4][1] = {};
      mm_stream<4, 1, 1280, 32>(LW2F, sQ, uvb, lane8, acc);
      mm_bias<4, 1, 1>(BBF01, sA1, 512, uvb, lane8, acc);
#pragma unroll
      for (int p = 0; p < 4; ++p)
#pragma unroll
        for (int ii = 0; ii < 4; ++ii) {
          int j = p >> 1, g = p & 1;
          size_t ob = (size_t)(b0 + g * 16 + q * 4 + ii) * 6400;
          int uv = uvb * 16 + col;
          out[ob + (uv >> 4) * 80 + 32 + 3 * (uv & 15) + j] = acc[p][0][ii] * S3;
        }
    }
    {
      f32x4 acc[4][1] = {};
      mm_stream<4, 1, 1792, 32>(LW2F, sQ, uvb, lane8, acc);
      mm_bias<4, 1, 1>(BBF10, sA1, 512, uvb, lane8, acc);
#pragma unroll
      for (int p = 0; p < 4; ++p)
#pragma unroll
        for (int ii = 0; ii < 4; ++ii) {
          int j = p >> 1, g = p & 1;
          size_t ob = (size_t)(b0 + g * 16 + q * 4 + ii) * 6400;
          int uv = uvb * 16 + col;
          out[ob + (size_t)(32 + 3 * (uv >> 5) + j) * 80 + (uv & 31)] = acc[p][0][ii] * S3;
        }
    }
  }

  // ===== phase B pass 2: planes (j=2, g=0,1) ==============================
  __syncthreads();
  for (int i = t; i < 4096; i += 1024) {
    int pl = i >> 11, r = i & 2047;       // pl = g
    const u32x4* src = (const u32x4*)(QF + ((size_t)(s * 2 + pl) * 4 + 3) * 16384);
    ((u32x4*)sQ)[pl * 2048 + r] = __builtin_nontemporal_load(src + r);
  }
  __syncthreads();
  {
    int uvb = h * 16 + slot;
    {
      f32x4 acc[2][1] = {};
      mm_stream<2, 1, 1280, 32>(LW2F, sQ, uvb, lane8, acc);
      mm_bias<2, 1, 1>(BBF01, sA1 + 4 * 512, 512, uvb, lane8, acc);
#pragma unroll
      for (int g = 0; g < 2; ++g)
#pragma unroll
        for (int ii = 0; ii < 4; ++ii) {
          size_t ob = (size_t)(b0 + g * 16 + q * 4 + ii) * 6400;
          int uv = uvb * 16 + col;
          out[ob + (uv >> 4) * 80 + 32 + 3 * (uv & 15) + 2] = acc[g][0][ii] * S3;
        }
    }
    {
      f32x4 acc[2][1] = {};
      mm_stream<2, 1, 1792, 32>(LW2F, sQ, uvb, lane8, acc);
      mm_bias<2, 1, 1>(BBF10, sA1 + 4 * 512, 512, uvb, lane8, acc);
#pragma unroll
      for (int g = 0; g < 2; ++g)
#pragma unroll
        for (int ii = 0; ii < 4; ++ii) {
          size_t ob = (size_t)(b0 + g * 16 + q * 4 + ii) * 6400;
          int uv = uvb * 16 + col;
          out[ob + (size_t)(32 + 3 * (uv >> 5) + 2) * 80 + (uv & 31)] = acc[g][0][ii] * S3;
        }
    }
  }
}

// ---------------------------------------------------------------------------
extern "C" void kernel_launch(void* const* d_in, const int* in_sizes, int n_in,
                              void* d_out, int out_size, void* d_ws, size_t ws_size,
                              hipStream_t stream) {
  const float* feat = (const float*)d_in[0];
  const float* ne   = (const float*)d_in[1];
  const float* W0   = (const float*)d_in[2];
  const float* W1   = (const float*)d_in[3];
  const float* lw1  = (const float*)d_in[4];
  const float* lb1  = (const float*)d_in[5];
  const float* lw2  = (const float*)d_in[6];
  const float* lb2  = (const float*)d_in[7];
  const float* bw1  = (const float*)d_in[8];
  const float* bb1  = (const float*)d_in[9];
  const float* bw2  = (const float*)d_in[10];
  const float* bb2  = (const float*)d_in[11];

  char* ws = (char*)d_ws;
  short* LW2F  = (short*)ws; ws += (size_t)36864 * 64 * 2;   // 4.72 MB
  short* BBF00 = (short*)ws; ws += (size_t)98304 * 2;
  short* BBF11 = (short*)ws; ws += (size_t)24576 * 2;
  short* BBF01 = (short*)ws; ws += (size_t)16384 * 2;
  short* BBF10 = (short*)ws; ws += (size_t)16384 * 2;
  float* H  = (float*)ws;   ws += (size_t)4096 * 64 * 4;
  float* H2 = (float*)ws;   ws += (size_t)4096 * 64 * 4;
  float* X0 = (float*)ws;   ws += (size_t)4096 * 16 * 4;
  float* X1 = (float*)ws;   ws += (size_t)4096 * 48 * 4;
  short* QF  = (short*)ws;  ws += (size_t)256 * 65536 * 2;   // 33.55 MB
  short* AbF = (short*)ws;  ws += (size_t)256 * 1536 * 2;
  short* A1F = (short*)ws;  ws += (size_t)256 * 1536 * 2;
  (void)ws_size; (void)in_sizes; (void)n_in; (void)out_size;

  hipLaunchKernelGGL(k_transpose, dim3(576), dim3(256), 0, stream, lw2, LW2F);
  hipLaunchKernelGGL(k_bias, dim3(608), dim3(256), 0, stream, bw2, lb2, bb2,
                     BBF00, BBF11, BBF01, BBF10);
  hipLaunchKernelGGL(k_samples, dim3(4096), dim3(192), 0, stream,
                     feat, ne, W0, W1, lw1, lb1, bw1, bb1, H, H2, X0, X1);
  hipLaunchKernelGGL(k_q, dim3(2048), dim3(256), 0, stream,
                     H, H2, X0, X1, QF, AbF, A1F);
  hipLaunchKernelGGL(k_main, dim3(256), dim3(1024), 0, stream,
                     LW2F, BBF00, BBF11, BBF01, BBF10, QF, AbF, A1F, (float*)d_out);
}